// Round 1
// 7372.125 us; speedup vs baseline: 1.1181x; 1.1181x over previous
//
#include <hip/hip_runtime.h>
#include <math.h>

constexpr int NB  = 64;    // batch
constexpr int NH  = 512;   // hidden
constexpr int BOSTOK = 2;

__device__ __forceinline__ float sigmoidf_(float x) { return 1.0f / (1.0f + expf(-x)); }

// ---------------------------------------------------------------------------
// init: eT = emb_dec[BOS] broadcast, k-major layout eT[k*NB+b]
__global__ __launch_bounds__(256) void k_init(float* __restrict__ eT,
                                              const float* __restrict__ emb_dec) {
    int i = blockIdx.x * 256 + threadIdx.x;
    if (i < NH * NB) eT[i] = emb_dec[BOSTOK * NH + (i >> 6)];
}

// ---------------------------------------------------------------------------
// Gather encoder embeddings row-major: xg[tb][k] = emb_enc[tok[tb]][k]
__global__ __launch_bounds__(256) void k_xg(const int* __restrict__ tokens,
                                            const float* __restrict__ emb,
                                            float* __restrict__ xg, int total_f4) {
    int idx = blockIdx.x * 256 + threadIdx.x;
    int stride = gridDim.x * 256;
    for (int f = idx; f < total_f4; f += stride) {
        const int tb = f >> 7;           // 128 float4 per row (NH/4)
        const int kq = f & 127;
        const int row = tokens[tb];
        ((float4*)xg)[f] = ((const float4*)(emb + (size_t)row * NH))[kq];
    }
}

// ---------------------------------------------------------------------------
// Pack Whh into quad layout: Wp[(g*128+kq)*512 + j] = float4 Whh[g*512+j][4kq..4kq+3]
// -> recurrence lane j loads float4 (4 consecutive k) fully coalesced across j.
__global__ __launch_bounds__(256) void k_wpack(const float* __restrict__ Whh,
                                               float4* __restrict__ Wp) {
    const int gk = blockIdx.x;            // 0..383 = g*128 + kq
    const int g = gk >> 7, kq = gk & 127;
    for (int j = threadIdx.x; j < NH; j += 256) {
        const float* src = Whh + ((size_t)(g * NH + j)) * NH + 4 * kq;
        Wp[(size_t)gk * NH + j] = make_float4(src[0], src[1], src[2], src[3]);
    }
}

// ---------------------------------------------------------------------------
// gi GEMM: gi[tb][gj] = sum_k xg[tb][k] * Wih[gj][k]
// M = T*B (tiles of 64 = one t), N = 1536 (tiles of 128), K = 512 (chunks of 16).
// Double-buffered LDS, one sync per chunk. Biases added later in recurrence.
__global__ __launch_bounds__(256) void k_gi(const float* __restrict__ xg,
                                            const float* __restrict__ Wih,
                                            float* __restrict__ gi) {
    __shared__ __align__(16) float At[2][16][68];    // [k][tb], padded stride
    __shared__ __align__(16) float Bs[2][16][132];   // [k][gj], padded stride
    const int tid  = threadIdx.x;
    const int tb0  = blockIdx.y * 64;
    const int gj0  = blockIdx.x * 128;
    const int g_tb = tid >> 4;            // 0..15 -> 4 tb rows
    const int g_gj = tid & 15;            // 0..15 -> 8 gj cols
    // staging maps
    const int a_tb = tid >> 2, a_kq = tid & 3;       // At: 1 float4/thread
    const int b_gj = tid >> 2, b_kq = tid & 3;       // Bs: 2 float4/thread

    float4 ra, rb0, rb1;
    ra  = *(const float4*)(xg  + (size_t)(tb0 + a_tb) * NH + 4 * a_kq);
    rb0 = *(const float4*)(Wih + (size_t)(gj0 + b_gj) * NH + 4 * b_kq);
    rb1 = *(const float4*)(Wih + (size_t)(gj0 + b_gj + 64) * NH + 4 * b_kq);

    float acc[4][8];
#pragma unroll
    for (int a = 0; a < 4; ++a)
#pragma unroll
        for (int b = 0; b < 8; ++b) acc[a][b] = 0.f;

    for (int c = 0; c < NH / 16; ++c) {
        const int buf = c & 1;
#pragma unroll
        for (int q = 0; q < 4; ++q) {
            At[buf][4 * a_kq + q][a_tb]      = ((const float*)&ra)[q];
            Bs[buf][4 * b_kq + q][b_gj]      = ((const float*)&rb0)[q];
            Bs[buf][4 * b_kq + q][b_gj + 64] = ((const float*)&rb1)[q];
        }
        __syncthreads();
        if (c + 1 < NH / 16) {
            const int k0 = (c + 1) * 16;
            ra  = *(const float4*)(xg  + (size_t)(tb0 + a_tb) * NH + k0 + 4 * a_kq);
            rb0 = *(const float4*)(Wih + (size_t)(gj0 + b_gj) * NH + k0 + 4 * b_kq);
            rb1 = *(const float4*)(Wih + (size_t)(gj0 + b_gj + 64) * NH + k0 + 4 * b_kq);
        }
#pragma unroll
        for (int k = 0; k < 16; ++k) {
            const float4 av = *(const float4*)&At[buf][k][4 * g_tb];
            const float4 b0 = *(const float4*)&Bs[buf][k][8 * g_gj];
            const float4 b1 = *(const float4*)&Bs[buf][k][8 * g_gj + 4];
            const float* ap  = (const float*)&av;
            const float* bp0 = (const float*)&b0;
            const float* bp1 = (const float*)&b1;
#pragma unroll
            for (int a = 0; a < 4; ++a) {
#pragma unroll
                for (int b = 0; b < 4; ++b) {
                    acc[a][b]     += ap[a] * bp0[b];
                    acc[a][b + 4] += ap[a] * bp1[b];
                }
            }
        }
    }
    float* go = gi + (size_t)tb0 * (3 * NH) + gj0;
#pragma unroll
    for (int a = 0; a < 4; ++a) {
        float4 s0 = make_float4(acc[a][0], acc[a][1], acc[a][2], acc[a][3]);
        float4 s1 = make_float4(acc[a][4], acc[a][5], acc[a][6], acc[a][7]);
        float* r = go + (size_t)(4 * g_tb + a) * (3 * NH) + 8 * g_gj;
        *(float4*)(r)     = s0;
        *(float4*)(r + 4) = s1;
    }
}

// ---------------------------------------------------------------------------
// BARRIER-FREE recurrence: one block per batch element (recurrence is
// batch-diagonal). h in LDS double-buffer; 1 __syncthreads per step; block
// exits at len[b] (h frozen thereafter, matching packed-sequence semantics).
// Thread j computes all 3 gate dots for its j via quad-packed Whh.
__global__ __launch_bounds__(512, 1) void k_enc_recur(
        const float* __restrict__ gi,          // [T*B][3H]
        const float4* __restrict__ Wp,         // [(g*128+kq)*512 + j]
        const float* __restrict__ bih, const float* __restrict__ bhh,
        const int* __restrict__ lengths,
        float* __restrict__ hfin) {            // k-major [j*NB+b]
    __shared__ __align__(16) float hbuf[2][NH];
    const int b = blockIdx.x;
    const int j = threadIdx.x;
    const int len = lengths[b];
    const float bir  = bih[j],          bhr = bhh[j];
    const float biz  = bih[NH + j],     bhz = bhh[NH + j];
    const float bin_ = bih[2 * NH + j], bhn = bhh[2 * NH + j];
    hbuf[0][j] = 0.f;
    __syncthreads();
    int cur = 0;
    for (int t = 0; t < len; ++t) {
        const float* __restrict__ hs = hbuf[cur];
        const float* __restrict__ gp = gi + ((size_t)t * NB + b) * (3 * NH);
        float ar = 0.f, az = 0.f, an = 0.f;
#pragma unroll 4
        for (int kq = 0; kq < NH / 4; ++kq) {
            const float4 hq = *(const float4*)&hs[4 * kq];           // LDS broadcast
            const float4 wr = Wp[(size_t)(0 * 128 + kq) * NH + j];   // coalesced
            const float4 wz = Wp[(size_t)(1 * 128 + kq) * NH + j];
            const float4 wn = Wp[(size_t)(2 * 128 + kq) * NH + j];
            ar += wr.x * hq.x + wr.y * hq.y + wr.z * hq.z + wr.w * hq.w;
            az += wz.x * hq.x + wz.y * hq.y + wz.z * hq.z + wz.w * hq.w;
            an += wn.x * hq.x + wn.y * hq.y + wn.z * hq.z + wn.w * hq.w;
        }
        const float r = sigmoidf_(gp[j] + bir + ar + bhr);
        const float z = sigmoidf_(gp[NH + j] + biz + az + bhz);
        const float n = tanhf(gp[2 * NH + j] + bin_ + r * (an + bhn));
        const float hv = (1.f - z) * n + z * hs[j];
        hbuf[cur ^ 1][j] = hv;
        __syncthreads();
        cur ^= 1;
    }
    hfin[(size_t)j * NB + b] = hbuf[cur][j];
}

// ---------------------------------------------------------------------------
// One decoder GRU step: weights wave-uniform (broadcast), e/h k-major coalesced.
// Writes h only in k-major layout (logits kernel consumes it directly now).
__global__ __launch_bounds__(256) void k_dec_gru(const float* __restrict__ hc,
                                                 float* __restrict__ hn,
                                                 const float* __restrict__ eT,
                                                 const float* __restrict__ Wih,
                                                 const float* __restrict__ Whh,
                                                 const float* __restrict__ bih,
                                                 const float* __restrict__ bhh) {
    const int tid = threadIdx.x;
    const int b = tid & 63;
    const int jj = tid >> 6;
    const int j = blockIdx.x * 4 + jj;
    const float* __restrict__ ir_w = Wih + (size_t)j * NH;
    const float* __restrict__ iz_w = Wih + (size_t)(NH + j) * NH;
    const float* __restrict__ in_w = Wih + (size_t)(2 * NH + j) * NH;
    const float* __restrict__ hr_w = Whh + (size_t)j * NH;
    const float* __restrict__ hz_w = Whh + (size_t)(NH + j) * NH;
    const float* __restrict__ hn_w = Whh + (size_t)(2 * NH + j) * NH;
    float air = 0.f, aiz = 0.f, ain = 0.f;
    float ahr = 0.f, ahz = 0.f, ahn = 0.f;
#pragma unroll 2
    for (int k = 0; k < NH; k += 4) {
        const float4 a4 = *(const float4*)(ir_w + k);
        const float4 b4 = *(const float4*)(iz_w + k);
        const float4 c4 = *(const float4*)(in_w + k);
        const float4 d4 = *(const float4*)(hr_w + k);
        const float4 e4 = *(const float4*)(hz_w + k);
        const float4 f4 = *(const float4*)(hn_w + k);
        const float e0 = eT[(k + 0) * NB + b];
        const float e1 = eT[(k + 1) * NB + b];
        const float e2 = eT[(k + 2) * NB + b];
        const float e3 = eT[(k + 3) * NB + b];
        const float h0 = hc[(k + 0) * NB + b];
        const float h1 = hc[(k + 1) * NB + b];
        const float h2 = hc[(k + 2) * NB + b];
        const float h3 = hc[(k + 3) * NB + b];
        air += a4.x * e0 + a4.y * e1 + a4.z * e2 + a4.w * e3;
        aiz += b4.x * e0 + b4.y * e1 + b4.z * e2 + b4.w * e3;
        ain += c4.x * e0 + c4.y * e1 + c4.z * e2 + c4.w * e3;
        ahr += d4.x * h0 + d4.y * h1 + d4.z * h2 + d4.w * h3;
        ahz += e4.x * h0 + e4.y * h1 + e4.z * h2 + e4.w * h3;
        ahn += f4.x * h0 + f4.y * h1 + f4.z * h2 + f4.w * h3;
    }
    const float hj = hc[j * NB + b];
    const float r = sigmoidf_(air + bih[j] + ahr + bhh[j]);
    const float z = sigmoidf_(aiz + bih[NH + j] + ahz + bhh[NH + j]);
    const float n = tanhf(ain + bih[2 * NH + j] + r * (ahn + bhh[2 * NH + j]));
    const float hv = (1.f - z) * n + z * hj;
    hn[j * NB + b] = hv;
}

// ---------------------------------------------------------------------------
// Logits GEMM (coalesced): C[b][v] = hT[:,b] . Wout[v,:] + bout[v]
// Block tile: 64 b x 128 v; K chunks of 32, double-buffered LDS (48 KB).
// hT is k-major [k*NB+b] -> chunk staging is a linear 8 KB copy.
__global__ __launch_bounds__(256) void k_logits(const float* __restrict__ hT,
                                                const float* __restrict__ Wout,
                                                const float* __restrict__ bout,
                                                float* __restrict__ outp, int V) {
    __shared__ __align__(16) float Ws[2][32][128];   // [k][v]
    __shared__ __align__(16) float Hs[2][32][64];    // [k][b]
    const int tid = threadIdx.x;
    const int v0 = blockIdx.x * 128;
    const int vg = tid & 31;     // 4 v each
    const int bg = tid >> 5;     // 8 b each
    const int w_vl = tid >> 3;   // 0..31 (+32p)
    const int w_kq = tid & 7;    // float4 within 32-k chunk

    float4 rw[4], rh[2];
#pragma unroll
    for (int p = 0; p < 4; ++p)
        rw[p] = *(const float4*)(Wout + (size_t)(v0 + w_vl + 32 * p) * NH + 4 * w_kq);
#pragma unroll
    for (int p = 0; p < 2; ++p)
        rh[p] = ((const float4*)hT)[p * 256 + tid];

    float acc[8][4];
#pragma unroll
    for (int i = 0; i < 8; ++i)
#pragma unroll
        for (int jv = 0; jv < 4; ++jv) acc[i][jv] = 0.f;

    for (int c = 0; c < 16; ++c) {
        const int buf = c & 1;
#pragma unroll
        for (int p = 0; p < 4; ++p)
#pragma unroll
            for (int q = 0; q < 4; ++q)
                Ws[buf][4 * w_kq + q][w_vl + 32 * p] = ((const float*)&rw[p])[q];
#pragma unroll
        for (int p = 0; p < 2; ++p)
            ((float4*)Hs[buf])[p * 256 + tid] = rh[p];
        __syncthreads();
        if (c + 1 < 16) {
            const int k0 = (c + 1) * 32;
#pragma unroll
            for (int p = 0; p < 4; ++p)
                rw[p] = *(const float4*)(Wout + (size_t)(v0 + w_vl + 32 * p) * NH + k0 + 4 * w_kq);
#pragma unroll
            for (int p = 0; p < 2; ++p)
                rh[p] = ((const float4*)(hT + (size_t)k0 * NB))[p * 256 + tid];
        }
#pragma unroll
        for (int k = 0; k < 32; ++k) {
            const float4 w  = *(const float4*)&Ws[buf][k][4 * vg];
            const float4 h0 = *(const float4*)&Hs[buf][k][8 * bg];
            const float4 h1 = *(const float4*)&Hs[buf][k][8 * bg + 4];
            const float* hp0 = (const float*)&h0;
            const float* hp1 = (const float*)&h1;
#pragma unroll
            for (int i = 0; i < 4; ++i) {
                acc[i][0] += hp0[i] * w.x; acc[i][1] += hp0[i] * w.y;
                acc[i][2] += hp0[i] * w.z; acc[i][3] += hp0[i] * w.w;
                acc[i + 4][0] += hp1[i] * w.x; acc[i + 4][1] += hp1[i] * w.y;
                acc[i + 4][2] += hp1[i] * w.z; acc[i + 4][3] += hp1[i] * w.w;
            }
        }
    }
    const float4 bo = *(const float4*)(bout + v0 + 4 * vg);
#pragma unroll
    for (int i = 0; i < 8; ++i) {
        float4 s = make_float4(acc[i][0] + bo.x, acc[i][1] + bo.y,
                               acc[i][2] + bo.z, acc[i][3] + bo.w);
        *(float4*)(outp + (size_t)(8 * bg + i) * V + v0 + 4 * vg) = s;
    }
}

// ---------------------------------------------------------------------------
// Argmax (np first-index tie-break) + next-token embedding gather (unchanged).
__global__ __launch_bounds__(256) void k_argmax_embed(const float* __restrict__ logits_t,
                                                      const float* __restrict__ emb_dec,
                                                      float* __restrict__ eT,
                                                      int V) {
    const int b = blockIdx.x;
    const int tid = threadIdx.x;
    const float* __restrict__ lp = logits_t + (size_t)b * V;
    float best = -INFINITY;
    int bi = 0x7fffffff;
    for (int v = tid; v < V; v += 256) {
        const float x = lp[v];
        if (x > best) { best = x; bi = v; }
    }
    __shared__ float sv[256];
    __shared__ int si[256];
    sv[tid] = best;
    si[tid] = bi;
    __syncthreads();
    for (int s = 128; s > 0; s >>= 1) {
        if (tid < s) {
            const float ov = sv[tid + s];
            const int oi = si[tid + s];
            if (ov > sv[tid] || (ov == sv[tid] && oi < si[tid])) { sv[tid] = ov; si[tid] = oi; }
        }
        __syncthreads();
    }
    const int tok = si[0];
    const float* __restrict__ er = emb_dec + (size_t)tok * NH;
    for (int k = tid; k < NH; k += 256)
        eT[k * NB + b] = er[k];
}

// ---------------------------------------------------------------------------
extern "C" void kernel_launch(void* const* d_in, const int* in_sizes, int n_in,
                              void* d_out, int out_size, void* d_ws, size_t ws_size,
                              hipStream_t stream) {
    const int*   batch_X = (const int*)d_in[0];
    const int*   lengths = (const int*)d_in[1];
    const float* emb_enc = (const float*)d_in[3];
    const float* Wih_e   = (const float*)d_in[4];
    const float* Whh_e   = (const float*)d_in[5];
    const float* bih_e   = (const float*)d_in[6];
    const float* bhh_e   = (const float*)d_in[7];
    const float* emb_dec = (const float*)d_in[8];
    const float* Wih_d   = (const float*)d_in[9];
    const float* Whh_d   = (const float*)d_in[10];
    const float* bih_d   = (const float*)d_in[11];
    const float* bhh_d   = (const float*)d_in[12];
    const float* Wout    = (const float*)d_in[13];
    const float* bout    = (const float*)d_in[14];

    const int T = in_sizes[0] / NB;            // 128
    const int V = in_sizes[14];                // 32000
    const int STEPS = out_size / (NB * V);     // 32

    float* out = (float*)d_out;

    // d_ws (proven >= 512 KB): decoder h ping-pong + eT (k-major each).
    float* dh0 = (float*)d_ws;
    float* dh1 = dh0 + NH * NB;
    float* eT  = dh1 + NH * NB;

    // Encoder-phase scratch in the TAIL of d_out (regions belong to logits of
    // steps s>=23, written long after encoder scratch is dead):
    //   xg (T*B*H), gi (T*B*3H), Whh packed (3*H*H), hfin (H*B).
    const size_t xg_off = (size_t)out_size - (size_t)T * NB * NH;
    const size_t gi_off = xg_off - (size_t)T * NB * 3 * NH;
    const size_t wp_off = gi_off - (size_t)3 * NH * NH;
    const size_t hf_off = wp_off - (size_t)NH * NB;
    float*  xg   = out + xg_off;
    float*  gi   = out + gi_off;
    float4* Wp   = (float4*)(out + wp_off);
    float*  hfin = out + hf_off;

    k_init<<<dim3(NH * NB / 256), dim3(256), 0, stream>>>(eT, emb_dec);
    k_xg<<<dim3(1024), dim3(256), 0, stream>>>(batch_X, emb_enc, xg, T * NB * NH / 4);
    k_wpack<<<dim3(3 * NH / 4), dim3(256), 0, stream>>>(Whh_e, Wp);
    k_gi<<<dim3(3 * NH / 128, T), dim3(256), 0, stream>>>(xg, Wih_e, gi);
    k_enc_recur<<<dim3(NB), dim3(512), 0, stream>>>(gi, Wp, bih_e, bhh_e, lengths, hfin);

    // Decoder: GRU -> logits -> argmax per step; h ping-pongs dh0/dh1 (k-major).
    const float* hc = hfin;
    for (int s = 0; s < STEPS; ++s) {
        float* hn = (s & 1) ? dh1 : dh0;
        k_dec_gru<<<dim3(NH / 4), dim3(256), 0, stream>>>(
            hc, hn, eT, Wih_d, Whh_d, bih_d, bhh_d);
        float* out_t = out + (size_t)s * NB * V;
        k_logits<<<dim3(V / 128), dim3(256), 0, stream>>>(hn, Wout, bout, out_t, V);
        if (s + 1 < STEPS)
            k_argmax_embed<<<dim3(NB), dim3(256), 0, stream>>>(out_t, emb_dec, eT, V);
        hc = hn;
    }
}

// Round 2
// 5928.019 us; speedup vs baseline: 1.3905x; 1.2436x over previous
//
#include <hip/hip_runtime.h>
#include <math.h>

constexpr int NB  = 64;    // batch
constexpr int NH  = 512;   // hidden
constexpr int BOSTOK = 2;
constexpr int JT = 16;     // j-tiles (32 j each)
constexpr int BT = 8;      // b-tiles (8 b each)

__device__ __forceinline__ float sigmoidf_(float x) { return 1.0f / (1.0f + expf(-x)); }

// Sum across the 16-lane DPP row (our reduce groups are lane bits 0..3).
__device__ __forceinline__ float rowsum16(float v) {
    int x;
    x = __builtin_amdgcn_mov_dpp(__float_as_int(v), 0x128, 0xf, 0xf, false); v += __int_as_float(x); // ror:8
    x = __builtin_amdgcn_mov_dpp(__float_as_int(v), 0x124, 0xf, 0xf, false); v += __int_as_float(x); // ror:4
    x = __builtin_amdgcn_mov_dpp(__float_as_int(v), 0x122, 0xf, 0xf, false); v += __int_as_float(x); // ror:2
    x = __builtin_amdgcn_mov_dpp(__float_as_int(v), 0x121, 0xf, 0xf, false); v += __int_as_float(x); // ror:1
    return v;
}

// ---------------------------------------------------------------------------
// init: eT = emb_dec[BOS] broadcast (k-major); zero the 8 group barriers
// (atomic sc-store so spin loads, which bypass L2, see the zeros).
__global__ __launch_bounds__(256) void k_init(float* __restrict__ eT,
                                              const float* __restrict__ emb_dec,
                                              int* __restrict__ bar) {
    int i = blockIdx.x * 256 + threadIdx.x;
    if (i < NH * NB) eT[i] = emb_dec[BOSTOK * NH + (i >> 6)];
    if (i < BT) __hip_atomic_store(&bar[i], 0, __ATOMIC_RELAXED, __HIP_MEMORY_SCOPE_AGENT);
}

// ---------------------------------------------------------------------------
// Gather encoder embeddings row-major: xg[tb][k] = emb_enc[tok[tb]][k]
__global__ __launch_bounds__(256) void k_xg(const int* __restrict__ tokens,
                                            const float* __restrict__ emb,
                                            float* __restrict__ xg, int total_f4) {
    int idx = blockIdx.x * 256 + threadIdx.x;
    int stride = gridDim.x * 256;
    for (int f = idx; f < total_f4; f += stride) {
        const int tb = f >> 7;           // 128 float4 per row (NH/4)
        const int kq = f & 127;
        const int row = tokens[tb];
        ((float4*)xg)[f] = ((const float4*)(emb + (size_t)row * NH))[kq];
    }
}

// ---------------------------------------------------------------------------
// gi GEMM: gi[tb][gj] = sum_k xg[tb][k] * Wih[gj][k]   (unchanged)
__global__ __launch_bounds__(256) void k_gi(const float* __restrict__ xg,
                                            const float* __restrict__ Wih,
                                            float* __restrict__ gi) {
    __shared__ __align__(16) float At[2][16][68];
    __shared__ __align__(16) float Bs[2][16][132];
    const int tid  = threadIdx.x;
    const int tb0  = blockIdx.y * 64;
    const int gj0  = blockIdx.x * 128;
    const int g_tb = tid >> 4;
    const int g_gj = tid & 15;
    const int a_tb = tid >> 2, a_kq = tid & 3;
    const int b_gj = tid >> 2, b_kq = tid & 3;

    float4 ra, rb0, rb1;
    ra  = *(const float4*)(xg  + (size_t)(tb0 + a_tb) * NH + 4 * a_kq);
    rb0 = *(const float4*)(Wih + (size_t)(gj0 + b_gj) * NH + 4 * b_kq);
    rb1 = *(const float4*)(Wih + (size_t)(gj0 + b_gj + 64) * NH + 4 * b_kq);

    float acc[4][8];
#pragma unroll
    for (int a = 0; a < 4; ++a)
#pragma unroll
        for (int b = 0; b < 8; ++b) acc[a][b] = 0.f;

    for (int c = 0; c < NH / 16; ++c) {
        const int buf = c & 1;
#pragma unroll
        for (int q = 0; q < 4; ++q) {
            At[buf][4 * a_kq + q][a_tb]      = ((const float*)&ra)[q];
            Bs[buf][4 * b_kq + q][b_gj]      = ((const float*)&rb0)[q];
            Bs[buf][4 * b_kq + q][b_gj + 64] = ((const float*)&rb1)[q];
        }
        __syncthreads();
        if (c + 1 < NH / 16) {
            const int k0 = (c + 1) * 16;
            ra  = *(const float4*)(xg  + (size_t)(tb0 + a_tb) * NH + k0 + 4 * a_kq);
            rb0 = *(const float4*)(Wih + (size_t)(gj0 + b_gj) * NH + k0 + 4 * b_kq);
            rb1 = *(const float4*)(Wih + (size_t)(gj0 + b_gj + 64) * NH + k0 + 4 * b_kq);
        }
#pragma unroll
        for (int k = 0; k < 16; ++k) {
            const float4 av = *(const float4*)&At[buf][k][4 * g_tb];
            const float4 b0 = *(const float4*)&Bs[buf][k][8 * g_gj];
            const float4 b1 = *(const float4*)&Bs[buf][k][8 * g_gj + 4];
            const float* ap  = (const float*)&av;
            const float* bp0 = (const float*)&b0;
            const float* bp1 = (const float*)&b1;
#pragma unroll
            for (int a = 0; a < 4; ++a) {
#pragma unroll
                for (int b = 0; b < 4; ++b) {
                    acc[a][b]     += ap[a] * bp0[b];
                    acc[a][b + 4] += ap[a] * bp1[b];
                }
            }
        }
    }
    float* go = gi + (size_t)tb0 * (3 * NH) + gj0;
#pragma unroll
    for (int a = 0; a < 4; ++a) {
        float4 s0 = make_float4(acc[a][0], acc[a][1], acc[a][2], acc[a][3]);
        float4 s1 = make_float4(acc[a][4], acc[a][5], acc[a][6], acc[a][7]);
        float* r = go + (size_t)(4 * g_tb + a) * (3 * NH) + 8 * g_gj;
        *(float4*)(r)     = s0;
        *(float4*)(r + 4) = s1;
    }
}

// ---------------------------------------------------------------------------
// Register-resident recurrence. 128 blocks = 16 j-tiles(32j) x 8 b-tiles(8b).
// Thread (jg,ks): jg=tid>>4 owns j pair {j0+2jg, j0+2jg+1}; ks=tid&15 owns
// k-slice [32ks,32ks+32). Whh slice (2jx3gx32k = 48 float4) lives in VGPRs for
// all 128 steps -> zero weight re-reads. Per step only h moves: coherent
// (sc0/sc1, relaxed-atomic) exchange through hx[b][j] + per-b-group 16-block
// counter. k-reduction via DPP row_ror (lanes 0..3 bits = ks). LDS h tile is
// quad-XOR-swizzled so ks-strided ds_read_b128 is 2-way (free).
__global__ __launch_bounds__(256, 1) void k_enc_recur(
        const float* __restrict__ gi,          // [T*NB][3NH]
        const float* __restrict__ Whh,
        const float* __restrict__ bih, const float* __restrict__ bhh,
        const int* __restrict__ lengths,
        float* __restrict__ hx,                // exchange, [b][j] 64x512
        int* __restrict__ bar,                 // [BT]
        float* __restrict__ hfin,              // k-major [j*NB+b]
        int T) {
    __shared__ __align__(16) float4 hsh[8 * 128];   // [b_local][pos], swizzled
    const int tid = threadIdx.x;
    const int jt = blockIdx.x >> 3;        // 0..15
    const int bt = blockIdx.x & 7;         // 0..7
    const int j0 = jt * 32;
    const int b0 = bt * 8;
    const int jg = tid >> 4;               // 0..15
    const int ks = tid & 15;               // 0..15
    const int k0 = ks * 32;

    // Output element owned by this thread (for gate math / store).
    const int jo = j0 + jg * 2 + (ks >> 3);
    const int bo = b0 + (ks & 7);

    // Persistent weights: wv[jl*3+g][quad]
    float4 wv[6][8];
#pragma unroll
    for (int jl = 0; jl < 2; ++jl)
#pragma unroll
        for (int g = 0; g < 3; ++g) {
            const float* wr = Whh + ((size_t)(g * NH + j0 + jg * 2 + jl)) * NH + k0;
#pragma unroll
            for (int q = 0; q < 8; ++q)
                wv[jl * 3 + g][q] = *(const float4*)(wr + 4 * q);
        }

    const float bir = bih[jo], biz = bih[NH + jo], bin_ = bih[2 * NH + jo];
    const float bhr = bhh[jo], bhz = bhh[NH + jo], bhn  = bhh[2 * NH + jo];
    const int   len = lengths[bo];
    const float* __restrict__ gpr = gi + (size_t)bo * (3 * NH) + jo;
    float hlast = 0.f;

    for (int t = 0; t < T; ++t) {
        // 1. wait for step t-1 h of this b-group (16 blocks)
        if (t > 0 && tid == 0) {
            const int tgt = JT * t;
            while (__hip_atomic_load(&bar[bt], __ATOMIC_RELAXED, __HIP_MEMORY_SCOPE_AGENT) < tgt)
                __builtin_amdgcn_s_sleep(1);
        }
        __syncthreads();

        // 2. stage h[b0..b0+7][:] into LDS at swizzled quad positions
        if (t == 0) {
#pragma unroll
            for (int i = 0; i < 4; ++i)
                hsh[tid + i * 256] = make_float4(0.f, 0.f, 0.f, 0.f);
        } else {
            float4 v[4];
#pragma unroll
            for (int i = 0; i < 4; ++i) {
                const int P = tid + i * 256;          // [8 b][128 pos]
                const int bl = P >> 7, p = P & 127;
                const int q = p ^ ((p >> 3) & 7);     // involution: src quad
                float* src = hx + (size_t)(b0 + bl) * NH + q * 4;
                v[i].x = __hip_atomic_load(src + 0, __ATOMIC_RELAXED, __HIP_MEMORY_SCOPE_AGENT);
                v[i].y = __hip_atomic_load(src + 1, __ATOMIC_RELAXED, __HIP_MEMORY_SCOPE_AGENT);
                v[i].z = __hip_atomic_load(src + 2, __ATOMIC_RELAXED, __HIP_MEMORY_SCOPE_AGENT);
                v[i].w = __hip_atomic_load(src + 3, __ATOMIC_RELAXED, __HIP_MEMORY_SCOPE_AGENT);
            }
#pragma unroll
            for (int i = 0; i < 4; ++i) {
                const int P = tid + i * 256;
                hsh[(P >> 7) * 128 + (P & 127)] = v[i];
            }
        }
        __syncthreads();

        // 3. compute: 8 b iterations; each: 8 ds_read_b128 + 192 FMA + DPP reduce
        float sr = 0.f, sz = 0.f, sn = 0.f;
#pragma unroll
        for (int b = 0; b < 8; ++b) {
            float4 hq[8];
#pragma unroll
            for (int kk = 0; kk < 8; ++kk) {
                const int q = ks * 8 + kk;
                hq[kk] = hsh[b * 128 + (q ^ (ks & 7))];
            }
            float pr0 = 0.f, pz0 = 0.f, pn0 = 0.f, pr1 = 0.f, pz1 = 0.f, pn1 = 0.f;
#pragma unroll
            for (int kk = 0; kk < 8; ++kk) {
                const float4 h4 = hq[kk];
                const float4 w0 = wv[0][kk], w1 = wv[1][kk], w2 = wv[2][kk];
                const float4 w3 = wv[3][kk], w4 = wv[4][kk], w5 = wv[5][kk];
                pr0 += w0.x * h4.x + w0.y * h4.y + w0.z * h4.z + w0.w * h4.w;
                pz0 += w1.x * h4.x + w1.y * h4.y + w1.z * h4.z + w1.w * h4.w;
                pn0 += w2.x * h4.x + w2.y * h4.y + w2.z * h4.z + w2.w * h4.w;
                pr1 += w3.x * h4.x + w3.y * h4.y + w3.z * h4.z + w3.w * h4.w;
                pz1 += w4.x * h4.x + w4.y * h4.y + w4.z * h4.z + w4.w * h4.w;
                pn1 += w5.x * h4.x + w5.y * h4.y + w5.z * h4.z + w5.w * h4.w;
            }
            pr0 = rowsum16(pr0); pz0 = rowsum16(pz0); pn0 = rowsum16(pn0);
            pr1 = rowsum16(pr1); pz1 = rowsum16(pz1); pn1 = rowsum16(pn1);
            if ((ks & 7) == b) {
                if (ks >> 3) { sr = pr1; sz = pz1; sn = pn1; }
                else         { sr = pr0; sz = pz0; sn = pn0; }
            }
        }

        // 4. gate math for (jo, bo); h_old from LDS
        const float* __restrict__ gp = gpr + (size_t)t * NB * (3 * NH);
        const float gr = gp[0], gz = gp[NH], gn = gp[2 * NH];
        const int qj = jo >> 2;
        const int pj = qj ^ ((qj >> 3) & 7);
        const float hold = ((const float*)&hsh[(ks & 7) * 128 + pj])[jo & 3];
        const float r = sigmoidf_(gr + bir + sr + bhr);
        const float z = sigmoidf_(gz + biz + sz + bhz);
        const float n = tanhf(gn + bin_ + r * (sn + bhn));
        const float hv = (1.f - z) * n + z * hold;
        if (t < len) {
            __hip_atomic_store(hx + (size_t)bo * NH + jo, hv,
                               __ATOMIC_RELAXED, __HIP_MEMORY_SCOPE_AGENT);
            hlast = hv;
        }
        __syncthreads();   // vmcnt(0): all this block's coherent stores drained
        if (tid == 0)
            __hip_atomic_fetch_add(&bar[bt], 1, __ATOMIC_RELAXED, __HIP_MEMORY_SCOPE_AGENT);
    }
    hfin[(size_t)jo * NB + bo] = hlast;
}

// ---------------------------------------------------------------------------
// One decoder GRU step (unchanged except readfirstlane on jj).
__global__ __launch_bounds__(256) void k_dec_gru(const float* __restrict__ hc,
                                                 float* __restrict__ hn,
                                                 const float* __restrict__ eT,
                                                 const float* __restrict__ Wih,
                                                 const float* __restrict__ Whh,
                                                 const float* __restrict__ bih,
                                                 const float* __restrict__ bhh) {
    const int tid = threadIdx.x;
    const int b = tid & 63;
    const int jj = __builtin_amdgcn_readfirstlane(tid >> 6);
    const int j = blockIdx.x * 4 + jj;
    const float* __restrict__ ir_w = Wih + (size_t)j * NH;
    const float* __restrict__ iz_w = Wih + (size_t)(NH + j) * NH;
    const float* __restrict__ in_w = Wih + (size_t)(2 * NH + j) * NH;
    const float* __restrict__ hr_w = Whh + (size_t)j * NH;
    const float* __restrict__ hz_w = Whh + (size_t)(NH + j) * NH;
    const float* __restrict__ hn_w = Whh + (size_t)(2 * NH + j) * NH;
    float air = 0.f, aiz = 0.f, ain = 0.f;
    float ahr = 0.f, ahz = 0.f, ahn = 0.f;
#pragma unroll 2
    for (int k = 0; k < NH; k += 4) {
        const float4 a4 = *(const float4*)(ir_w + k);
        const float4 b4 = *(const float4*)(iz_w + k);
        const float4 c4 = *(const float4*)(in_w + k);
        const float4 d4 = *(const float4*)(hr_w + k);
        const float4 e4 = *(const float4*)(hz_w + k);
        const float4 f4 = *(const float4*)(hn_w + k);
        const float e0 = eT[(k + 0) * NB + b];
        const float e1 = eT[(k + 1) * NB + b];
        const float e2 = eT[(k + 2) * NB + b];
        const float e3 = eT[(k + 3) * NB + b];
        const float h0 = hc[(k + 0) * NB + b];
        const float h1 = hc[(k + 1) * NB + b];
        const float h2 = hc[(k + 2) * NB + b];
        const float h3 = hc[(k + 3) * NB + b];
        air += a4.x * e0 + a4.y * e1 + a4.z * e2 + a4.w * e3;
        aiz += b4.x * e0 + b4.y * e1 + b4.z * e2 + b4.w * e3;
        ain += c4.x * e0 + c4.y * e1 + c4.z * e2 + c4.w * e3;
        ahr += d4.x * h0 + d4.y * h1 + d4.z * h2 + d4.w * h3;
        ahz += e4.x * h0 + e4.y * h1 + e4.z * h2 + e4.w * h3;
        ahn += f4.x * h0 + f4.y * h1 + f4.z * h2 + f4.w * h3;
    }
    const float hj = hc[j * NB + b];
    const float r = sigmoidf_(air + bih[j] + ahr + bhh[j]);
    const float z = sigmoidf_(aiz + bih[NH + j] + ahz + bhh[NH + j]);
    const float n = tanhf(ain + bih[2 * NH + j] + r * (ahn + bhh[2 * NH + j]));
    const float hv = (1.f - z) * n + z * hj;
    hn[j * NB + b] = hv;
}

// ---------------------------------------------------------------------------
// Logits GEMM (unchanged): C[b][v] = hT[:,b].Wout[v,:] + bout[v]
__global__ __launch_bounds__(256) void k_logits(const float* __restrict__ hT,
                                                const float* __restrict__ Wout,
                                                const float* __restrict__ bout,
                                                float* __restrict__ outp, int V) {
    __shared__ __align__(16) float Ws[2][32][128];
    __shared__ __align__(16) float Hs[2][32][64];
    const int tid = threadIdx.x;
    const int v0 = blockIdx.x * 128;
    const int vg = tid & 31;
    const int bg = tid >> 5;
    const int w_vl = tid >> 3;
    const int w_kq = tid & 7;

    float4 rw[4], rh[2];
#pragma unroll
    for (int p = 0; p < 4; ++p)
        rw[p] = *(const float4*)(Wout + (size_t)(v0 + w_vl + 32 * p) * NH + 4 * w_kq);
#pragma unroll
    for (int p = 0; p < 2; ++p)
        rh[p] = ((const float4*)hT)[p * 256 + tid];

    float acc[8][4];
#pragma unroll
    for (int i = 0; i < 8; ++i)
#pragma unroll
        for (int jv = 0; jv < 4; ++jv) acc[i][jv] = 0.f;

    for (int c = 0; c < 16; ++c) {
        const int buf = c & 1;
#pragma unroll
        for (int p = 0; p < 4; ++p)
#pragma unroll
            for (int q = 0; q < 4; ++q)
                Ws[buf][4 * w_kq + q][w_vl + 32 * p] = ((const float*)&rw[p])[q];
#pragma unroll
        for (int p = 0; p < 2; ++p)
            ((float4*)Hs[buf])[p * 256 + tid] = rh[p];
        __syncthreads();
        if (c + 1 < 16) {
            const int k0 = (c + 1) * 32;
#pragma unroll
            for (int p = 0; p < 4; ++p)
                rw[p] = *(const float4*)(Wout + (size_t)(v0 + w_vl + 32 * p) * NH + k0 + 4 * w_kq);
#pragma unroll
            for (int p = 0; p < 2; ++p)
                rh[p] = ((const float4*)(hT + (size_t)k0 * NB))[p * 256 + tid];
        }
#pragma unroll
        for (int k = 0; k < 32; ++k) {
            const float4 w  = *(const float4*)&Ws[buf][k][4 * vg];
            const float4 h0 = *(const float4*)&Hs[buf][k][8 * bg];
            const float4 h1 = *(const float4*)&Hs[buf][k][8 * bg + 4];
            const float* hp0 = (const float*)&h0;
            const float* hp1 = (const float*)&h1;
#pragma unroll
            for (int i = 0; i < 4; ++i) {
                acc[i][0] += hp0[i] * w.x; acc[i][1] += hp0[i] * w.y;
                acc[i][2] += hp0[i] * w.z; acc[i][3] += hp0[i] * w.w;
                acc[i + 4][0] += hp1[i] * w.x; acc[i + 4][1] += hp1[i] * w.y;
                acc[i + 4][2] += hp1[i] * w.z; acc[i + 4][3] += hp1[i] * w.w;
            }
        }
    }
    const float4 bo = *(const float4*)(bout + v0 + 4 * vg);
#pragma unroll
    for (int i = 0; i < 8; ++i) {
        float4 s = make_float4(acc[i][0] + bo.x, acc[i][1] + bo.y,
                               acc[i][2] + bo.z, acc[i][3] + bo.w);
        *(float4*)(outp + (size_t)(8 * bg + i) * V + v0 + 4 * vg) = s;
    }
}

// ---------------------------------------------------------------------------
// Argmax (np first-index tie-break) + next-token embedding gather (unchanged).
__global__ __launch_bounds__(256) void k_argmax_embed(const float* __restrict__ logits_t,
                                                      const float* __restrict__ emb_dec,
                                                      float* __restrict__ eT,
                                                      int V) {
    const int b = blockIdx.x;
    const int tid = threadIdx.x;
    const float* __restrict__ lp = logits_t + (size_t)b * V;
    float best = -INFINITY;
    int bi = 0x7fffffff;
    for (int v = tid; v < V; v += 256) {
        const float x = lp[v];
        if (x > best) { best = x; bi = v; }
    }
    __shared__ float sv[256];
    __shared__ int si[256];
    sv[tid] = best;
    si[tid] = bi;
    __syncthreads();
    for (int s = 128; s > 0; s >>= 1) {
        if (tid < s) {
            const float ov = sv[tid + s];
            const int oi = si[tid + s];
            if (ov > sv[tid] || (ov == sv[tid] && oi < si[tid])) { sv[tid] = ov; si[tid] = oi; }
        }
        __syncthreads();
    }
    const int tok = si[0];
    const float* __restrict__ er = emb_dec + (size_t)tok * NH;
    for (int k = tid; k < NH; k += 256)
        eT[k * NB + b] = er[k];
}

// ---------------------------------------------------------------------------
extern "C" void kernel_launch(void* const* d_in, const int* in_sizes, int n_in,
                              void* d_out, int out_size, void* d_ws, size_t ws_size,
                              hipStream_t stream) {
    const int*   batch_X = (const int*)d_in[0];
    const int*   lengths = (const int*)d_in[1];
    const float* emb_enc = (const float*)d_in[3];
    const float* Wih_e   = (const float*)d_in[4];
    const float* Whh_e   = (const float*)d_in[5];
    const float* bih_e   = (const float*)d_in[6];
    const float* bhh_e   = (const float*)d_in[7];
    const float* emb_dec = (const float*)d_in[8];
    const float* Wih_d   = (const float*)d_in[9];
    const float* Whh_d   = (const float*)d_in[10];
    const float* bih_d   = (const float*)d_in[11];
    const float* bhh_d   = (const float*)d_in[12];
    const float* Wout    = (const float*)d_in[13];
    const float* bout    = (const float*)d_in[14];

    const int T = in_sizes[0] / NB;            // 128
    const int V = in_sizes[14];                // 32000
    const int STEPS = out_size / (NB * V);     // 32

    float* out = (float*)d_out;

    // d_ws (>= 512 KB): decoder h ping-pong + eT + barrier counters.
    // hx (encoder h exchange) aliases dh0 — dead before decoder writes dh0.
    float* dh0 = (float*)d_ws;
    float* dh1 = dh0 + NH * NB;
    float* eT  = dh1 + NH * NB;
    int*   bar = (int*)(eT + NH * NB);
    float* hx  = dh0;

    // Encoder scratch in the TAIL of d_out (overwritten only by logits of
    // steps s>=30, long after encoder completes):
    const size_t xg_off = (size_t)out_size - (size_t)T * NB * NH;
    const size_t gi_off = xg_off - (size_t)T * NB * 3 * NH;
    const size_t hf_off = gi_off - (size_t)NH * NB;
    float* xg   = out + xg_off;
    float* gi   = out + gi_off;
    float* hfin = out + hf_off;

    k_init<<<dim3(NH * NB / 256), dim3(256), 0, stream>>>(eT, emb_dec, bar);
    k_xg<<<dim3(1024), dim3(256), 0, stream>>>(batch_X, emb_enc, xg, T * NB * NH / 4);
    k_gi<<<dim3(3 * NH / 128, T), dim3(256), 0, stream>>>(xg, Wih_e, gi);
    k_enc_recur<<<dim3(JT * BT), dim3(256), 0, stream>>>(
        gi, Whh_e, bih_e, bhh_e, lengths, hx, bar, hfin, T);

    // Decoder: GRU -> logits -> argmax per step; h ping-pongs dh0/dh1 (k-major).
    const float* hc = hfin;
    for (int s = 0; s < STEPS; ++s) {
        float* hn = (s & 1) ? dh1 : dh0;
        k_dec_gru<<<dim3(NH / 4), dim3(256), 0, stream>>>(
            hc, hn, eT, Wih_d, Whh_d, bih_d, bhh_d);
        float* out_t = out + (size_t)s * NB * V;
        k_logits<<<dim3(V / 128), dim3(256), 0, stream>>>(hn, Wout, bout, out_t, V);
        if (s + 1 < STEPS)
            k_argmax_embed<<<dim3(NB), dim3(256), 0, stream>>>(out_t, emb_dec, eT, V);
        hc = hn;
    }
}